// Round 1
// baseline (3197.834 us; speedup 1.0000x reference)
//
#include <hip/hip_runtime.h>
#include <math.h>

namespace {
constexpr int B = 16, T = 1024, F = 1024, H = 16, D = 64;
constexpr int NT = B * T;            // 16384 token rows
constexpr int QKV_COLS = 3 * F;      // 3072
constexpr size_t HEAD_ELEMS = (size_t)B * H * T * D;   // 16,777,216 floats
// workspace layout (floats):
constexpr size_t Q_OFF = 0;
constexpr size_t K_OFF = HEAD_ELEMS;          // reused as w-scratch after scores
constexpr size_t V_OFF = 2 * HEAD_ELEMS;
constexpr size_t S_OFF = 3 * HEAD_ELEMS;      // [B*H, 64, 64] score mats
constexpr size_t A_OFF = Q_OFF;               // a reuses dead q region
}

// ---------------------------------------------------------------------------
// Kernel 1: qkv = x @ W_attn + b_attn, scattered to q/k/v in [B,H,T,D] layout
// 64x64 tile, BK=16, 256 threads, 4x4 acc per thread.
// ---------------------------------------------------------------------------
__global__ __launch_bounds__(256) void qkv_gemm(
    const float* __restrict__ x, const float* __restrict__ Wa,
    const float* __restrict__ ba, float* __restrict__ qb,
    float* __restrict__ kb, float* __restrict__ vb) {
  __shared__ float xs[64][17];
  __shared__ float wsh[16][65];
  const int tid = threadIdx.x;
  const int row0 = blockIdx.y * 64;
  const int col0 = blockIdx.x * 64;
  const int ty = tid >> 4, tx = tid & 15;
  float acc[4][4] = {};
  for (int kc = 0; kc < F; kc += 16) {
#pragma unroll
    for (int i = 0; i < 4; ++i) {
      int idx = tid + i * 256;               // 0..1023
      int r = idx >> 4, c = idx & 15;
      xs[r][c] = x[(size_t)(row0 + r) * F + kc + c];
    }
#pragma unroll
    for (int i = 0; i < 4; ++i) {
      int idx = tid + i * 256;
      int r = idx >> 6, c = idx & 63;
      wsh[r][c] = Wa[(size_t)(kc + r) * QKV_COLS + col0 + c];
    }
    __syncthreads();
#pragma unroll
    for (int kk = 0; kk < 16; ++kk) {
      float av[4], bv[4];
#pragma unroll
      for (int i = 0; i < 4; ++i) av[i] = xs[ty * 4 + i][kk];
#pragma unroll
      for (int j = 0; j < 4; ++j) bv[j] = wsh[kk][tx * 4 + j];
#pragma unroll
      for (int i = 0; i < 4; ++i)
#pragma unroll
        for (int j = 0; j < 4; ++j) acc[i][j] += av[i] * bv[j];
    }
    __syncthreads();
  }
  // epilogue: bias + scatter into q/k/v [B,H,T,D]
#pragma unroll
  for (int i = 0; i < 4; ++i) {
    int row = row0 + ty * 4 + i;
    int b = row >> 10, t = row & 1023;
#pragma unroll
    for (int j = 0; j < 4; ++j) {
      int col = col0 + tx * 4 + j;
      float val = acc[i][j] + ba[col];
      int part = col >> 10;
      int f = col & 1023;
      int h = f >> 6, dd = f & 63;
      float* dst = (part == 0) ? qb : (part == 1) ? kb : vb;
      dst[(((size_t)b * H + h) * T + t) * D + dd] = val;
    }
  }
}

// ---------------------------------------------------------------------------
// Kernel 2: s[b,h,d,e] = sum_t q[b,h,t,d]*k[b,h,t,e] / 8, tril-masked.
// One block per (b,h). LDS-staged 64-row T chunks.
// ---------------------------------------------------------------------------
__global__ __launch_bounds__(256) void score_kernel(
    const float* __restrict__ qb, const float* __restrict__ kb,
    float* __restrict__ sb) {
  __shared__ float qs[64][65];
  __shared__ float ks[64][65];
  const int bh = blockIdx.x;
  const int tid = threadIdx.x;
  const size_t base = (size_t)bh * T * D;
  const int d0 = (tid >> 4) * 4, e0 = (tid & 15) * 4;
  float acc[4][4] = {};
  for (int ch = 0; ch < T / 64; ++ch) {
#pragma unroll
    for (int i = 0; i < 16; ++i) {
      int idx = tid + i * 256;               // 0..4095
      qs[idx >> 6][idx & 63] = qb[base + (size_t)ch * 4096 + idx];
      ks[idx >> 6][idx & 63] = kb[base + (size_t)ch * 4096 + idx];
    }
    __syncthreads();
#pragma unroll 8
    for (int tt = 0; tt < 64; ++tt) {
      float qa[4], kv[4];
#pragma unroll
      for (int i = 0; i < 4; ++i) qa[i] = qs[tt][d0 + i];
#pragma unroll
      for (int j = 0; j < 4; ++j) kv[j] = ks[tt][e0 + j];
#pragma unroll
      for (int i = 0; i < 4; ++i)
#pragma unroll
        for (int j = 0; j < 4; ++j) acc[i][j] += qa[i] * kv[j];
    }
    __syncthreads();
  }
#pragma unroll
  for (int i = 0; i < 4; ++i) {
#pragma unroll
    for (int j = 0; j < 4; ++j) {
      int dd = d0 + i, ee = e0 + j;
      float v = acc[i][j] * 0.125f;          // / sqrt(64)
      if (ee > dd) v = -10000.0f;            // tril mask
      sb[(size_t)bh * (D * D) + dd * D + ee] = v;
    }
  }
}

// ---------------------------------------------------------------------------
// Kernel 3: w[t,d] = (s[d,:] . v[t,:]) / 4096 + mask[b,t]; softmax over t;
// out2 = merged w; a = w*v (merged layout) for the proj GEMM.
// One block per (b,h); thread (trow=tid/64, d=tid%64) owns t-stripe.
// ---------------------------------------------------------------------------
__global__ __launch_bounds__(256) void softmax_kernel(
    const float* __restrict__ vb, const float* __restrict__ sb,
    const float* __restrict__ mask, float* __restrict__ wraw,
    float* __restrict__ ab, float* __restrict__ out2) {
  __shared__ float sl[64][65];
  __shared__ float red[4][64];
  __shared__ float stat[64];
  const int bh = blockIdx.x;
  const int b = bh >> 4, h = bh & 15;
  const int tid = threadIdx.x;
  const int trow = tid >> 6, d = tid & 63;
  const size_t vbase = (size_t)bh * T * D;
#pragma unroll
  for (int i = 0; i < 16; ++i) {
    int idx = tid + i * 256;
    sl[idx >> 6][idx & 63] = sb[(size_t)bh * (D * D) + idx];
  }
  __syncthreads();
  const float* mrow = mask + (size_t)b * T;
  // pass 1: compute raw w, track per-d max over t
  float m = -1e30f;
  for (int t = trow; t < T; t += 4) {
    const float* vr = vb + vbase + (size_t)t * D;
    float acc = 0.f;
#pragma unroll
    for (int e = 0; e < 64; ++e) acc += sl[d][e] * vr[e];
    float w = acc * (1.0f / 4096.0f) + mrow[t];
    wraw[vbase + (size_t)t * D + d] = w;
    m = fmaxf(m, w);
  }
  red[trow][d] = m;
  __syncthreads();
  if (trow == 0)
    stat[d] = fmaxf(fmaxf(red[0][d], red[1][d]), fmaxf(red[2][d], red[3][d]));
  __syncthreads();
  // pass 2: exponentiate, track per-d sum
  float mx = stat[d];
  float ssum = 0.f;
  for (int t = trow; t < T; t += 4) {
    size_t hidx = vbase + (size_t)t * D + d;
    float ex = __expf(wraw[hidx] - mx);
    wraw[hidx] = ex;
    ssum += ex;
  }
  red[trow][d] = ssum;
  __syncthreads();
  if (trow == 0) stat[d] = red[0][d] + red[1][d] + red[2][d] + red[3][d];
  __syncthreads();
  // pass 3: normalize, emit out2 and a = w*v in merged [B,T,F] layout
  float inv = 1.0f / stat[d];
  for (int t = trow; t < T; t += 4) {
    size_t hidx = vbase + (size_t)t * D + d;
    float ex = wraw[hidx] * inv;
    float vv = vb[hidx];
    size_t oidx = ((size_t)b * T + t) * F + h * D + d;
    out2[oidx] = ex;
    ab[oidx] = ex * vv;
  }
}

// ---------------------------------------------------------------------------
// Kernel 4: out1 = a @ W_proj + b_proj   [16384x1024] @ [1024x1024]
// ---------------------------------------------------------------------------
__global__ __launch_bounds__(256) void proj_gemm(
    const float* __restrict__ ab, const float* __restrict__ Wp,
    const float* __restrict__ bp, float* __restrict__ out1) {
  __shared__ float xs[64][17];
  __shared__ float wsh[16][65];
  const int tid = threadIdx.x;
  const int row0 = blockIdx.y * 64;
  const int col0 = blockIdx.x * 64;
  const int ty = tid >> 4, tx = tid & 15;
  float acc[4][4] = {};
  for (int kc = 0; kc < F; kc += 16) {
#pragma unroll
    for (int i = 0; i < 4; ++i) {
      int idx = tid + i * 256;
      int r = idx >> 4, c = idx & 15;
      xs[r][c] = ab[(size_t)(row0 + r) * F + kc + c];
    }
#pragma unroll
    for (int i = 0; i < 4; ++i) {
      int idx = tid + i * 256;
      int r = idx >> 6, c = idx & 63;
      wsh[r][c] = Wp[(size_t)(kc + r) * F + col0 + c];
    }
    __syncthreads();
#pragma unroll
    for (int kk = 0; kk < 16; ++kk) {
      float av[4], bv[4];
#pragma unroll
      for (int i = 0; i < 4; ++i) av[i] = xs[ty * 4 + i][kk];
#pragma unroll
      for (int j = 0; j < 4; ++j) bv[j] = wsh[kk][tx * 4 + j];
#pragma unroll
      for (int i = 0; i < 4; ++i)
#pragma unroll
        for (int j = 0; j < 4; ++j) acc[i][j] += av[i] * bv[j];
    }
    __syncthreads();
  }
#pragma unroll
  for (int i = 0; i < 4; ++i) {
    int row = row0 + ty * 4 + i;
#pragma unroll
    for (int j = 0; j < 4; ++j) {
      int col = col0 + tx * 4 + j;
      out1[(size_t)row * F + col] = acc[i][j] + bp[col];
    }
  }
}

extern "C" void kernel_launch(void* const* d_in, const int* in_sizes, int n_in,
                              void* d_out, int out_size, void* d_ws,
                              size_t ws_size, hipStream_t stream) {
  const float* x = (const float*)d_in[0];
  const float* mask = (const float*)d_in[1];
  const float* Wa = (const float*)d_in[2];
  const float* ba = (const float*)d_in[3];
  const float* Wp = (const float*)d_in[4];
  const float* bp = (const float*)d_in[5];
  float* ws = (float*)d_ws;
  float* out = (float*)d_out;

  float* qb = ws + Q_OFF;
  float* kb = ws + K_OFF;
  float* vb = ws + V_OFF;
  float* sb = ws + S_OFF;
  float* wraw = ws + K_OFF;  // k is dead after score_kernel
  float* ab = ws + A_OFF;    // q is dead after score_kernel

  dim3 g1(QKV_COLS / 64, NT / 64);
  qkv_gemm<<<g1, 256, 0, stream>>>(x, Wa, ba, qb, kb, vb);

  score_kernel<<<dim3(B * H), 256, 0, stream>>>(qb, kb, sb);

  softmax_kernel<<<dim3(B * H), 256, 0, stream>>>(
      vb, sb, mask, wraw, ab, out + (size_t)NT * F);

  proj_gemm<<<dim3(F / 64, NT / 64), 256, 0, stream>>>(ab, Wp, bp, out);
}

// Round 3
// 945.936 us; speedup vs baseline: 3.3806x; 3.3806x over previous
//
#include <hip/hip_runtime.h>
#include <math.h>

namespace {
constexpr int B = 16, T = 1024, F = 1024, H = 16, D = 64;
constexpr int NT = B * T;            // 16384 token rows
constexpr int QKV_COLS = 3 * F;      // 3072

// workspace layout (bytes). Proven ws_size >= 205.5 MB (round-1 used that).
constexpr size_t XHI_OFF = 0;                    // bf16 x hi      33,554,432
constexpr size_t XLO_OFF = 33554432;             // bf16 x lo      33,554,432
constexpr size_t WAH_OFF = 67108864;             // bf16 Wa^T hi    6,291,456
constexpr size_t WVL_OFF = 73400320;             // bf16 Wv^T lo    2,097,152
constexpr size_t QB_OFF  = 75497472;             // bf16 q         33,554,432
constexpr size_t KB_OFF  = 109051904;            // bf16 k         33,554,432
constexpr size_t SB_OFF  = 142606336;            // f32 s           4,194,304
constexpr size_t AB_OFF  = 146800640;            // bf16 a         33,554,432
constexpr size_t WPB_OFF = 180355072;            // bf16 Wp^T       2,097,152
// total 182,452,224 bytes
// overlays: vb (f32, 67MB) = QB..KB span (q,k dead after score);
//           wraw (f32, 67MB) = XHI..XLO span (x dead after v_mfma)
constexpr size_t VB_OFF   = QB_OFF;
constexpr size_t WRAW_OFF = XHI_OFF;
}

typedef __attribute__((ext_vector_type(8))) __bf16 bf16x8;
typedef __attribute__((ext_vector_type(4))) float f32x4;

__device__ __forceinline__ unsigned short f2bf(float f) {
  unsigned u = __builtin_bit_cast(unsigned, f);
  u += 0x7FFFu + ((u >> 16) & 1u);
  return (unsigned short)(u >> 16);
}
__device__ __forceinline__ float bf2f(unsigned short s) {
  return __builtin_bit_cast(float, (unsigned)s << 16);
}
__device__ __forceinline__ void gld16(const unsigned short* g, unsigned short* l) {
  __builtin_amdgcn_global_load_lds(
      (const __attribute__((address_space(1))) unsigned int*)g,
      (__attribute__((address_space(3))) unsigned int*)l, 16, 0, 0);
}

// ---------------------------------------------------------------------------
// cast x fp32 -> bf16 hi + bf16 lo (split precision)
// ---------------------------------------------------------------------------
__global__ __launch_bounds__(256) void cast_x(const float* __restrict__ x,
                                              unsigned short* __restrict__ xhi,
                                              unsigned short* __restrict__ xlo) {
  int i = (blockIdx.x * 256 + threadIdx.x) * 4;
  float4 v = *(const float4*)&x[i];
  ushort4 h, l;
  h.x = f2bf(v.x); l.x = f2bf(v.x - bf2f(h.x));
  h.y = f2bf(v.y); l.y = f2bf(v.y - bf2f(h.y));
  h.z = f2bf(v.z); l.z = f2bf(v.z - bf2f(h.z));
  h.w = f2bf(v.w); l.w = f2bf(v.w - bf2f(h.w));
  *(ushort4*)&xhi[i] = h;
  *(ushort4*)&xlo[i] = l;
}

// ---------------------------------------------------------------------------
// transpose-cast W [1024][ncols] fp32 -> Wt_hi [ncols][1024] bf16;
// for cols >= locol0 also emit lo residual into Wlo[(col-locol0)][1024].
// ---------------------------------------------------------------------------
__global__ __launch_bounds__(256) void tcast(const float* __restrict__ W,
                                             unsigned short* __restrict__ Wt,
                                             unsigned short* __restrict__ Wlo,
                                             int ncols, int locol0) {
  __shared__ float tile[64][65];
  const int bx = blockIdx.x, by = blockIdx.y, tid = threadIdx.x;
#pragma unroll
  for (int i = 0; i < 16; ++i) {
    int idx = tid + i * 256;
    int r = idx >> 6, c = idx & 63;
    tile[r][c] = W[(size_t)(by * 64 + r) * ncols + bx * 64 + c];
  }
  __syncthreads();
#pragma unroll
  for (int i = 0; i < 16; ++i) {
    int idx = tid + i * 256;
    int r = idx >> 6, c = idx & 63;
    int col = bx * 64 + r;
    float w = tile[c][r];
    unsigned short h = f2bf(w);
    Wt[(size_t)col * 1024 + by * 64 + c] = h;
    if (col >= locol0) {
      Wlo[(size_t)(col - locol0) * 1024 + by * 64 + c] = f2bf(w - bf2f(h));
    }
  }
}

// ---------------------------------------------------------------------------
// q,k GEMM: bf16 MFMA, 128x128 tile, BK=32. A=[16384][1024] bf16 hi,
// Bt = Wa^T rows 0..2047. Writes q,k bf16 in [B,H,T,D].
// ---------------------------------------------------------------------------
__global__ __launch_bounds__(256) void qk_mfma(
    const unsigned short* __restrict__ A, const unsigned short* __restrict__ Bt,
    const float* __restrict__ ba, unsigned short* __restrict__ qb,
    unsigned short* __restrict__ kb) {
  __shared__ __align__(16) unsigned short Alds[4096];
  __shared__ __align__(16) unsigned short Blds[4096];
  const int tid = threadIdx.x;
  const int wave = tid >> 6, lane = tid & 63;
  const int quad = lane >> 4, m16 = lane & 15;
  const int wr = wave >> 1, wc = wave & 1;
  const int row0 = blockIdx.y * 128, col0 = blockIdx.x * 128;
  const int mA = tid & 127, hi = tid >> 7;
  const unsigned short* Abase = A + (size_t)(row0 + mA) * 1024 + hi * 8;
  const unsigned short* Bbase = Bt + (size_t)(col0 + mA) * 1024 + hi * 8;
  f32x4 acc[4][4] = {};
  for (int kc = 0; kc < 1024; kc += 32) {
    gld16(Abase + kc,      &Alds[wave * 512]);
    gld16(Abase + kc + 16, &Alds[2048 + wave * 512]);
    gld16(Bbase + kc,      &Blds[wave * 512]);
    gld16(Bbase + kc + 16, &Blds[2048 + wave * 512]);
    __syncthreads();
    bf16x8 af[4], bfr[4];
#pragma unroll
    for (int mi = 0; mi < 4; ++mi)
      af[mi] = *(const bf16x8*)&Alds[quad * 1024 + (wr * 64 + mi * 16 + m16) * 8];
#pragma unroll
    for (int ni = 0; ni < 4; ++ni)
      bfr[ni] = *(const bf16x8*)&Blds[quad * 1024 + (wc * 64 + ni * 16 + m16) * 8];
#pragma unroll
    for (int mi = 0; mi < 4; ++mi)
#pragma unroll
      for (int ni = 0; ni < 4; ++ni)
        acc[mi][ni] = __builtin_amdgcn_mfma_f32_16x16x32_bf16(
            af[mi], bfr[ni], acc[mi][ni], 0, 0, 0);
    __syncthreads();
  }
  const int part = col0 >> 10;  // 0 = q, 1 = k
#pragma unroll
  for (int mi = 0; mi < 4; ++mi) {
#pragma unroll
    for (int ni = 0; ni < 4; ++ni) {
      int gcol = col0 + wc * 64 + ni * 16 + m16;
      int f = gcol & 1023;
      int h = f >> 6, dd = f & 63;
      float bias = ba[gcol];
#pragma unroll
      for (int r = 0; r < 4; ++r) {
        int grow = row0 + wr * 64 + mi * 16 + quad * 4 + r;
        int b = grow >> 10, t = grow & 1023;
        size_t hidx = (((size_t)b * H + h) * T + t) * D + dd;
        float val = acc[mi][ni][r] + bias;
        if (part == 0) qb[hidx] = f2bf(val);
        else kb[hidx] = f2bf(val);
      }
    }
  }
}

// ---------------------------------------------------------------------------
// v GEMM with split precision: v = xh@Wh + xh@Wl + xl@Wh  (fp32 out).
// Bt_hi = Wa^T rows 2048..3071, Bt_lo = Wv^T lo. Writes vb fp32 [B,H,T,D].
// ---------------------------------------------------------------------------
__global__ __launch_bounds__(256) void v_mfma(
    const unsigned short* __restrict__ Ah, const unsigned short* __restrict__ Al,
    const unsigned short* __restrict__ Bh, const unsigned short* __restrict__ Bl,
    const float* __restrict__ ba, float* __restrict__ vb) {
  __shared__ __align__(16) unsigned short AldsH[4096];
  __shared__ __align__(16) unsigned short AldsL[4096];
  __shared__ __align__(16) unsigned short BldsH[4096];
  __shared__ __align__(16) unsigned short BldsL[4096];
  const int tid = threadIdx.x;
  const int wave = tid >> 6, lane = tid & 63;
  const int quad = lane >> 4, m16 = lane & 15;
  const int wr = wave >> 1, wc = wave & 1;
  const int row0 = blockIdx.y * 128, col0 = blockIdx.x * 128;
  const int mA = tid & 127, hi = tid >> 7;
  const size_t aoff = (size_t)(row0 + mA) * 1024 + hi * 8;
  const size_t boff = (size_t)(col0 + mA) * 1024 + hi * 8;
  f32x4 acc[4][4] = {};
  for (int kc = 0; kc < 1024; kc += 32) {
    gld16(Ah + aoff + kc,      &AldsH[wave * 512]);
    gld16(Ah + aoff + kc + 16, &AldsH[2048 + wave * 512]);
    gld16(Al + aoff + kc,      &AldsL[wave * 512]);
    gld16(Al + aoff + kc + 16, &AldsL[2048 + wave * 512]);
    gld16(Bh + boff + kc,      &BldsH[wave * 512]);
    gld16(Bh + boff + kc + 16, &BldsH[2048 + wave * 512]);
    gld16(Bl + boff + kc,      &BldsL[wave * 512]);
    gld16(Bl + boff + kc + 16, &BldsL[2048 + wave * 512]);
    __syncthreads();
#pragma unroll
    for (int mi = 0; mi < 4; ++mi) {
      int aidx = quad * 1024 + (wr * 64 + mi * 16 + m16) * 8;
      bf16x8 ah = *(const bf16x8*)&AldsH[aidx];
      bf16x8 al = *(const bf16x8*)&AldsL[aidx];
#pragma unroll
      for (int ni = 0; ni < 4; ++ni) {
        int bidx = quad * 1024 + (wc * 64 + ni * 16 + m16) * 8;
        bf16x8 bh = *(const bf16x8*)&BldsH[bidx];
        bf16x8 bl = *(const bf16x8*)&BldsL[bidx];
        acc[mi][ni] = __builtin_amdgcn_mfma_f32_16x16x32_bf16(ah, bh, acc[mi][ni], 0, 0, 0);
        acc[mi][ni] = __builtin_amdgcn_mfma_f32_16x16x32_bf16(ah, bl, acc[mi][ni], 0, 0, 0);
        acc[mi][ni] = __builtin_amdgcn_mfma_f32_16x16x32_bf16(al, bh, acc[mi][ni], 0, 0, 0);
      }
    }
    __syncthreads();
  }
#pragma unroll
  for (int mi = 0; mi < 4; ++mi) {
#pragma unroll
    for (int ni = 0; ni < 4; ++ni) {
      int gcol = col0 + wc * 64 + ni * 16 + m16;   // 0..1023 within v
      int h = gcol >> 6, dd = gcol & 63;
      float bias = ba[2048 + gcol];
#pragma unroll
      for (int r = 0; r < 4; ++r) {
        int grow = row0 + wr * 64 + mi * 16 + quad * 4 + r;
        int b = grow >> 10, t = grow & 1023;
        vb[(((size_t)b * H + h) * T + t) * D + dd] = acc[mi][ni][r] + bias;
      }
    }
  }
}

// ---------------------------------------------------------------------------
// proj GEMM: out1 = a @ Wp + bp (bf16 MFMA, fp32 out)
// ---------------------------------------------------------------------------
__global__ __launch_bounds__(256) void proj_mfma(
    const unsigned short* __restrict__ A, const unsigned short* __restrict__ Bt,
    const float* __restrict__ bp, float* __restrict__ out1) {
  __shared__ __align__(16) unsigned short Alds[4096];
  __shared__ __align__(16) unsigned short Blds[4096];
  const int tid = threadIdx.x;
  const int wave = tid >> 6, lane = tid & 63;
  const int quad = lane >> 4, m16 = lane & 15;
  const int wr = wave >> 1, wc = wave & 1;
  const int row0 = blockIdx.y * 128, col0 = blockIdx.x * 128;
  const int mA = tid & 127, hi = tid >> 7;
  const unsigned short* Abase = A + (size_t)(row0 + mA) * 1024 + hi * 8;
  const unsigned short* Bbase = Bt + (size_t)(col0 + mA) * 1024 + hi * 8;
  f32x4 acc[4][4] = {};
  for (int kc = 0; kc < 1024; kc += 32) {
    gld16(Abase + kc,      &Alds[wave * 512]);
    gld16(Abase + kc + 16, &Alds[2048 + wave * 512]);
    gld16(Bbase + kc,      &Blds[wave * 512]);
    gld16(Bbase + kc + 16, &Blds[2048 + wave * 512]);
    __syncthreads();
    bf16x8 af[4], bfr[4];
#pragma unroll
    for (int mi = 0; mi < 4; ++mi)
      af[mi] = *(const bf16x8*)&Alds[quad * 1024 + (wr * 64 + mi * 16 + m16) * 8];
#pragma unroll
    for (int ni = 0; ni < 4; ++ni)
      bfr[ni] = *(const bf16x8*)&Blds[quad * 1024 + (wc * 64 + ni * 16 + m16) * 8];
#pragma unroll
    for (int mi = 0; mi < 4; ++mi)
#pragma unroll
      for (int ni = 0; ni < 4; ++ni)
        acc[mi][ni] = __builtin_amdgcn_mfma_f32_16x16x32_bf16(
            af[mi], bfr[ni], acc[mi][ni], 0, 0, 0);
    __syncthreads();
  }
#pragma unroll
  for (int mi = 0; mi < 4; ++mi) {
#pragma unroll
    for (int ni = 0; ni < 4; ++ni) {
      int gcol = col0 + wc * 64 + ni * 16 + m16;
      float bias = bp[gcol];
#pragma unroll
      for (int r = 0; r < 4; ++r) {
        int grow = row0 + wr * 64 + mi * 16 + quad * 4 + r;
        out1[(size_t)grow * F + gcol] = acc[mi][ni][r] + bias;
      }
    }
  }
}

// ---------------------------------------------------------------------------
// s[b,h,d,e] = sum_t q[t,d]*k[t,e] / 8, tril-masked. q,k bf16.
// ---------------------------------------------------------------------------
__global__ __launch_bounds__(256) void score_kernel(
    const unsigned short* __restrict__ qb, const unsigned short* __restrict__ kb,
    float* __restrict__ sb) {
  __shared__ float qs[64][65];
  __shared__ float ks[64][65];
  const int bh = blockIdx.x;
  const int tid = threadIdx.x;
  const size_t base = (size_t)bh * T * D;
  const int d0 = (tid >> 4) * 4, e0 = (tid & 15) * 4;
  float acc[4][4] = {};
  for (int ch = 0; ch < T / 64; ++ch) {
#pragma unroll
    for (int i = 0; i < 4; ++i) {
      int idx = (tid + i * 256) * 4;
      ushort4 qv = *(const ushort4*)&qb[base + (size_t)ch * 4096 + idx];
      ushort4 kv = *(const ushort4*)&kb[base + (size_t)ch * 4096 + idx];
      int r = idx >> 6, c = idx & 63;
      qs[r][c] = bf2f(qv.x); qs[r][c+1] = bf2f(qv.y);
      qs[r][c+2] = bf2f(qv.z); qs[r][c+3] = bf2f(qv.w);
      ks[r][c] = bf2f(kv.x); ks[r][c+1] = bf2f(kv.y);
      ks[r][c+2] = bf2f(kv.z); ks[r][c+3] = bf2f(kv.w);
    }
    __syncthreads();
#pragma unroll 8
    for (int tt = 0; tt < 64; ++tt) {
      float qa[4], kv[4];
#pragma unroll
      for (int i = 0; i < 4; ++i) qa[i] = qs[tt][d0 + i];
#pragma unroll
      for (int j = 0; j < 4; ++j) kv[j] = ks[tt][e0 + j];
#pragma unroll
      for (int i = 0; i < 4; ++i)
#pragma unroll
        for (int j = 0; j < 4; ++j) acc[i][j] += qa[i] * kv[j];
    }
    __syncthreads();
  }
#pragma unroll
  for (int i = 0; i < 4; ++i) {
#pragma unroll
    for (int j = 0; j < 4; ++j) {
      int dd = d0 + i, ee = e0 + j;
      float v = acc[i][j] * 0.125f;
      if (ee > dd) v = -10000.0f;
      sb[(size_t)bh * (D * D) + dd * D + ee] = v;
    }
  }
}

// ---------------------------------------------------------------------------
// w = s.v/4096 + mask; softmax over t; out2 = w merged; ab = bf16(w*v) merged
// ---------------------------------------------------------------------------
__global__ __launch_bounds__(256) void softmax_kernel(
    const float* __restrict__ vb, const float* __restrict__ sb,
    const float* __restrict__ mask, float* __restrict__ wraw,
    unsigned short* __restrict__ ab, float* __restrict__ out2) {
  __shared__ float sl[64][65];
  __shared__ float red[4][64];
  __shared__ float stat[64];
  const int bh = blockIdx.x;
  const int b = bh >> 4, h = bh & 15;
  const int tid = threadIdx.x;
  const int trow = tid >> 6, d = tid & 63;
  const size_t vbase = (size_t)bh * T * D;
#pragma unroll
  for (int i = 0; i < 16; ++i) {
    int idx = tid + i * 256;
    sl[idx >> 6][idx & 63] = sb[(size_t)bh * (D * D) + idx];
  }
  __syncthreads();
  const float* mrow = mask + (size_t)b * T;
  float m = -1e30f;
  for (int t = trow; t < T; t += 4) {
    const float* vr = vb + vbase + (size_t)t * D;
    float acc = 0.f;
#pragma unroll
    for (int e = 0; e < 64; ++e) acc += sl[d][e] * vr[e];
    float w = acc * (1.0f / 4096.0f) + mrow[t];
    wraw[vbase + (size_t)t * D + d] = w;
    m = fmaxf(m, w);
  }
  red[trow][d] = m;
  __syncthreads();
  if (trow == 0)
    stat[d] = fmaxf(fmaxf(red[0][d], red[1][d]), fmaxf(red[2][d], red[3][d]));
  __syncthreads();
  float mx = stat[d];
  float ssum = 0.f;
  for (int t = trow; t < T; t += 4) {
    size_t hidx = vbase + (size_t)t * D + d;
    float ex = __expf(wraw[hidx] - mx);
    wraw[hidx] = ex;
    ssum += ex;
  }
  red[trow][d] = ssum;
  __syncthreads();
  if (trow == 0) stat[d] = red[0][d] + red[1][d] + red[2][d] + red[3][d];
  __syncthreads();
  float inv = 1.0f / stat[d];
  for (int t = trow; t < T; t += 4) {
    size_t hidx = vbase + (size_t)t * D + d;
    float ex = wraw[hidx] * inv;
    float vv = vb[hidx];
    size_t oidx = ((size_t)b * T + t) * F + h * D + d;
    out2[oidx] = ex;
    ab[oidx] = f2bf(ex * vv);
  }
}

extern "C" void kernel_launch(void* const* d_in, const int* in_sizes, int n_in,
                              void* d_out, int out_size, void* d_ws,
                              size_t ws_size, hipStream_t stream) {
  const float* x = (const float*)d_in[0];
  const float* mask = (const float*)d_in[1];
  const float* Wa = (const float*)d_in[2];
  const float* ba = (const float*)d_in[3];
  const float* Wp = (const float*)d_in[4];
  const float* bp = (const float*)d_in[5];
  char* ws = (char*)d_ws;
  float* out = (float*)d_out;

  unsigned short* xhi = (unsigned short*)(ws + XHI_OFF);
  unsigned short* xlo = (unsigned short*)(ws + XLO_OFF);
  unsigned short* Wah = (unsigned short*)(ws + WAH_OFF);
  unsigned short* Wvl = (unsigned short*)(ws + WVL_OFF);
  unsigned short* qb  = (unsigned short*)(ws + QB_OFF);
  unsigned short* kb  = (unsigned short*)(ws + KB_OFF);
  float* sb   = (float*)(ws + SB_OFF);
  unsigned short* ab  = (unsigned short*)(ws + AB_OFF);
  unsigned short* Wpb = (unsigned short*)(ws + WPB_OFF);
  float* vb   = (float*)(ws + VB_OFF);     // overlays q,k (dead after score)
  float* wraw = (float*)(ws + WRAW_OFF);   // overlays x hi/lo (dead after v)

  cast_x<<<NT * F / 1024, 256, 0, stream>>>(x, xhi, xlo);
  tcast<<<dim3(QKV_COLS / 64, F / 64), 256, 0, stream>>>(Wa, Wah, Wvl,
                                                         QKV_COLS, 2048);
  tcast<<<dim3(F / 64, F / 64), 256, 0, stream>>>(Wp, Wpb, Wvl, F, 1 << 30);

  qk_mfma<<<dim3(2048 / 128, NT / 128), 256, 0, stream>>>(xhi, Wah, ba, qb, kb);

  score_kernel<<<dim3(B * H), 256, 0, stream>>>(qb, kb, sb);

  // q,k now dead -> vb overlays them
  v_mfma<<<dim3(F / 128, NT / 128), 256, 0, stream>>>(
      xhi, xlo, Wah + (size_t)2048 * 1024, Wvl, ba, vb);

  softmax_kernel<<<dim3(B * H), 256, 0, stream>>>(
      vb, sb, mask, wraw, ab, out + (size_t)NT * F);

  proj_mfma<<<dim3(F / 128, NT / 128), 256, 0, stream>>>(ab, Wpb, bp, out);
}

// Round 4
// 755.002 us; speedup vs baseline: 4.2355x; 1.2529x over previous
//
#include <hip/hip_runtime.h>
#include <math.h>

namespace {
constexpr int B = 16, T = 1024, F = 1024, H = 16, D = 64;
constexpr int NT = B * T;            // 16384 token rows
constexpr int QKV_COLS = 3 * F;      // 3072

// workspace layout (bytes). Proven ws_size >= 182,452,224 (round-3 used that).
constexpr size_t XHI_OFF = 0;                    // bf16 x hi      33,554,432
constexpr size_t XLO_OFF = 33554432;             // bf16 x lo      33,554,432
constexpr size_t WAH_OFF = 67108864;             // bf16 Wa^T hi    6,291,456
constexpr size_t WVL_OFF = 73400320;             // bf16 Wv^T lo    2,097,152
constexpr size_t QB_OFF  = 75497472;             // bf16 q         33,554,432
constexpr size_t KB_OFF  = 109051904;            // bf16 k         33,554,432
constexpr size_t SB_OFF  = 142606336;            // f32 s           4,194,304
constexpr size_t AB_OFF  = 146800640;            // bf16 a         33,554,432
constexpr size_t WPB_OFF = 180355072;            // bf16 Wp^T       2,097,152
// total 182,452,224 bytes
// overlays: vb (f32, 67MB) = QB..KB span (q,k dead after score);
//           wraw (f32, 67MB) = XHI..XLO span (x dead after v_mfma);
//           sp partial sums (f32, 256KB) = WVL span (Wv_lo dead after v_mfma)
constexpr size_t VB_OFF   = QB_OFF;
constexpr size_t WRAW_OFF = XHI_OFF;
constexpr size_t SP_OFF   = WVL_OFF;
}

typedef __attribute__((ext_vector_type(8))) __bf16 bf16x8;
typedef __attribute__((ext_vector_type(4))) float f32x4;

__device__ __forceinline__ unsigned short f2bf(float f) {
  unsigned u = __builtin_bit_cast(unsigned, f);
  u += 0x7FFFu + ((u >> 16) & 1u);
  return (unsigned short)(u >> 16);
}
__device__ __forceinline__ float bf2f(unsigned short s) {
  return __builtin_bit_cast(float, (unsigned)s << 16);
}
__device__ __forceinline__ void gld16(const unsigned short* g, unsigned short* l) {
  __builtin_amdgcn_global_load_lds(
      (const __attribute__((address_space(1))) unsigned int*)g,
      (__attribute__((address_space(3))) unsigned int*)l, 16, 0, 0);
}

// ---------------------------------------------------------------------------
// cast x fp32 -> bf16 hi + bf16 lo (split precision)
// ---------------------------------------------------------------------------
__global__ __launch_bounds__(256) void cast_x(const float* __restrict__ x,
                                              unsigned short* __restrict__ xhi,
                                              unsigned short* __restrict__ xlo) {
  int i = (blockIdx.x * 256 + threadIdx.x) * 4;
  float4 v = *(const float4*)&x[i];
  ushort4 h, l;
  h.x = f2bf(v.x); l.x = f2bf(v.x - bf2f(h.x));
  h.y = f2bf(v.y); l.y = f2bf(v.y - bf2f(h.y));
  h.z = f2bf(v.z); l.z = f2bf(v.z - bf2f(h.z));
  h.w = f2bf(v.w); l.w = f2bf(v.w - bf2f(h.w));
  *(ushort4*)&xhi[i] = h;
  *(ushort4*)&xlo[i] = l;
}

// ---------------------------------------------------------------------------
// transpose-cast W [1024][ncols] fp32 -> Wt_hi [ncols][1024] bf16;
// for cols >= locol0 also emit lo residual into Wlo[(col-locol0)][1024].
// ---------------------------------------------------------------------------
__global__ __launch_bounds__(256) void tcast(const float* __restrict__ W,
                                             unsigned short* __restrict__ Wt,
                                             unsigned short* __restrict__ Wlo,
                                             int ncols, int locol0) {
  __shared__ float tile[64][65];
  const int bx = blockIdx.x, by = blockIdx.y, tid = threadIdx.x;
#pragma unroll
  for (int i = 0; i < 16; ++i) {
    int idx = tid + i * 256;
    int r = idx >> 6, c = idx & 63;
    tile[r][c] = W[(size_t)(by * 64 + r) * ncols + bx * 64 + c];
  }
  __syncthreads();
#pragma unroll
  for (int i = 0; i < 16; ++i) {
    int idx = tid + i * 256;
    int r = idx >> 6, c = idx & 63;
    int col = bx * 64 + r;
    float w = tile[c][r];
    unsigned short h = f2bf(w);
    Wt[(size_t)col * 1024 + by * 64 + c] = h;
    if (col >= locol0) {
      Wlo[(size_t)(col - locol0) * 1024 + by * 64 + c] = f2bf(w - bf2f(h));
    }
  }
}

// ---------------------------------------------------------------------------
// q,k GEMM: bf16 MFMA, 128x128 tile, BK=32.
// ---------------------------------------------------------------------------
__global__ __launch_bounds__(256) void qk_mfma(
    const unsigned short* __restrict__ A, const unsigned short* __restrict__ Bt,
    const float* __restrict__ ba, unsigned short* __restrict__ qb,
    unsigned short* __restrict__ kb) {
  __shared__ __align__(16) unsigned short Alds[4096];
  __shared__ __align__(16) unsigned short Blds[4096];
  const int tid = threadIdx.x;
  const int wave = tid >> 6, lane = tid & 63;
  const int quad = lane >> 4, m16 = lane & 15;
  const int wr = wave >> 1, wc = wave & 1;
  const int row0 = blockIdx.y * 128, col0 = blockIdx.x * 128;
  const int mA = tid & 127, hi = tid >> 7;
  const unsigned short* Abase = A + (size_t)(row0 + mA) * 1024 + hi * 8;
  const unsigned short* Bbase = Bt + (size_t)(col0 + mA) * 1024 + hi * 8;
  f32x4 acc[4][4] = {};
  for (int kc = 0; kc < 1024; kc += 32) {
    gld16(Abase + kc,      &Alds[wave * 512]);
    gld16(Abase + kc + 16, &Alds[2048 + wave * 512]);
    gld16(Bbase + kc,      &Blds[wave * 512]);
    gld16(Bbase + kc + 16, &Blds[2048 + wave * 512]);
    __syncthreads();
    bf16x8 af[4], bfr[4];
#pragma unroll
    for (int mi = 0; mi < 4; ++mi)
      af[mi] = *(const bf16x8*)&Alds[quad * 1024 + (wr * 64 + mi * 16 + m16) * 8];
#pragma unroll
    for (int ni = 0; ni < 4; ++ni)
      bfr[ni] = *(const bf16x8*)&Blds[quad * 1024 + (wc * 64 + ni * 16 + m16) * 8];
#pragma unroll
    for (int mi = 0; mi < 4; ++mi)
#pragma unroll
      for (int ni = 0; ni < 4; ++ni)
        acc[mi][ni] = __builtin_amdgcn_mfma_f32_16x16x32_bf16(
            af[mi], bfr[ni], acc[mi][ni], 0, 0, 0);
    __syncthreads();
  }
  const int part = col0 >> 10;  // 0 = q, 1 = k
#pragma unroll
  for (int mi = 0; mi < 4; ++mi) {
#pragma unroll
    for (int ni = 0; ni < 4; ++ni) {
      int gcol = col0 + wc * 64 + ni * 16 + m16;
      int f = gcol & 1023;
      int h = f >> 6, dd = f & 63;
      float bias = ba[gcol];
#pragma unroll
      for (int r = 0; r < 4; ++r) {
        int grow = row0 + wr * 64 + mi * 16 + quad * 4 + r;
        int b = grow >> 10, t = grow & 1023;
        size_t hidx = (((size_t)b * H + h) * T + t) * D + dd;
        float val = acc[mi][ni][r] + bias;
        if (part == 0) qb[hidx] = f2bf(val);
        else kb[hidx] = f2bf(val);
      }
    }
  }
}

// ---------------------------------------------------------------------------
// v GEMM with split precision: v = xh@Wh + xh@Wl + xl@Wh  (fp32 out).
// ---------------------------------------------------------------------------
__global__ __launch_bounds__(256) void v_mfma(
    const unsigned short* __restrict__ Ah, const unsigned short* __restrict__ Al,
    const unsigned short* __restrict__ Bh, const unsigned short* __restrict__ Bl,
    const float* __restrict__ ba, float* __restrict__ vb) {
  __shared__ __align__(16) unsigned short AldsH[4096];
  __shared__ __align__(16) unsigned short AldsL[4096];
  __shared__ __align__(16) unsigned short BldsH[4096];
  __shared__ __align__(16) unsigned short BldsL[4096];
  const int tid = threadIdx.x;
  const int wave = tid >> 6, lane = tid & 63;
  const int quad = lane >> 4, m16 = lane & 15;
  const int wr = wave >> 1, wc = wave & 1;
  const int row0 = blockIdx.y * 128, col0 = blockIdx.x * 128;
  const int mA = tid & 127, hi = tid >> 7;
  const size_t aoff = (size_t)(row0 + mA) * 1024 + hi * 8;
  const size_t boff = (size_t)(col0 + mA) * 1024 + hi * 8;
  f32x4 acc[4][4] = {};
  for (int kc = 0; kc < 1024; kc += 32) {
    gld16(Ah + aoff + kc,      &AldsH[wave * 512]);
    gld16(Ah + aoff + kc + 16, &AldsH[2048 + wave * 512]);
    gld16(Al + aoff + kc,      &AldsL[wave * 512]);
    gld16(Al + aoff + kc + 16, &AldsL[2048 + wave * 512]);
    gld16(Bh + boff + kc,      &BldsH[wave * 512]);
    gld16(Bh + boff + kc + 16, &BldsH[2048 + wave * 512]);
    gld16(Bl + boff + kc,      &BldsL[wave * 512]);
    gld16(Bl + boff + kc + 16, &BldsL[2048 + wave * 512]);
    __syncthreads();
#pragma unroll
    for (int mi = 0; mi < 4; ++mi) {
      int aidx = quad * 1024 + (wr * 64 + mi * 16 + m16) * 8;
      bf16x8 ah = *(const bf16x8*)&AldsH[aidx];
      bf16x8 al = *(const bf16x8*)&AldsL[aidx];
#pragma unroll
      for (int ni = 0; ni < 4; ++ni) {
        int bidx = quad * 1024 + (wc * 64 + ni * 16 + m16) * 8;
        bf16x8 bh = *(const bf16x8*)&BldsH[bidx];
        bf16x8 bl = *(const bf16x8*)&BldsL[bidx];
        acc[mi][ni] = __builtin_amdgcn_mfma_f32_16x16x32_bf16(ah, bh, acc[mi][ni], 0, 0, 0);
        acc[mi][ni] = __builtin_amdgcn_mfma_f32_16x16x32_bf16(ah, bl, acc[mi][ni], 0, 0, 0);
        acc[mi][ni] = __builtin_amdgcn_mfma_f32_16x16x32_bf16(al, bh, acc[mi][ni], 0, 0, 0);
      }
    }
    __syncthreads();
  }
#pragma unroll
  for (int mi = 0; mi < 4; ++mi) {
#pragma unroll
    for (int ni = 0; ni < 4; ++ni) {
      int gcol = col0 + wc * 64 + ni * 16 + m16;
      int h = gcol >> 6, dd = gcol & 63;
      float bias = ba[2048 + gcol];
#pragma unroll
      for (int r = 0; r < 4; ++r) {
        int grow = row0 + wr * 64 + mi * 16 + quad * 4 + r;
        int b = grow >> 10, t = grow & 1023;
        vb[(((size_t)b * H + h) * T + t) * D + dd] = acc[mi][ni][r] + bias;
      }
    }
  }
}

// ---------------------------------------------------------------------------
// proj GEMM: out1 = a @ Wp + bp (bf16 MFMA, fp32 out)
// ---------------------------------------------------------------------------
__global__ __launch_bounds__(256) void proj_mfma(
    const unsigned short* __restrict__ A, const unsigned short* __restrict__ Bt,
    const float* __restrict__ bp, float* __restrict__ out1) {
  __shared__ __align__(16) unsigned short Alds[4096];
  __shared__ __align__(16) unsigned short Blds[4096];
  const int tid = threadIdx.x;
  const int wave = tid >> 6, lane = tid & 63;
  const int quad = lane >> 4, m16 = lane & 15;
  const int wr = wave >> 1, wc = wave & 1;
  const int row0 = blockIdx.y * 128, col0 = blockIdx.x * 128;
  const int mA = tid & 127, hi = tid >> 7;
  const unsigned short* Abase = A + (size_t)(row0 + mA) * 1024 + hi * 8;
  const unsigned short* Bbase = Bt + (size_t)(col0 + mA) * 1024 + hi * 8;
  f32x4 acc[4][4] = {};
  for (int kc = 0; kc < 1024; kc += 32) {
    gld16(Abase + kc,      &Alds[wave * 512]);
    gld16(Abase + kc + 16, &Alds[2048 + wave * 512]);
    gld16(Bbase + kc,      &Blds[wave * 512]);
    gld16(Bbase + kc + 16, &Blds[2048 + wave * 512]);
    __syncthreads();
    bf16x8 af[4], bfr[4];
#pragma unroll
    for (int mi = 0; mi < 4; ++mi)
      af[mi] = *(const bf16x8*)&Alds[quad * 1024 + (wr * 64 + mi * 16 + m16) * 8];
#pragma unroll
    for (int ni = 0; ni < 4; ++ni)
      bfr[ni] = *(const bf16x8*)&Blds[quad * 1024 + (wc * 64 + ni * 16 + m16) * 8];
#pragma unroll
    for (int mi = 0; mi < 4; ++mi)
#pragma unroll
      for (int ni = 0; ni < 4; ++ni)
        acc[mi][ni] = __builtin_amdgcn_mfma_f32_16x16x32_bf16(
            af[mi], bfr[ni], acc[mi][ni], 0, 0, 0);
    __syncthreads();
  }
#pragma unroll
  for (int mi = 0; mi < 4; ++mi) {
#pragma unroll
    for (int ni = 0; ni < 4; ++ni) {
      int gcol = col0 + wc * 64 + ni * 16 + m16;
      float bias = bp[gcol];
#pragma unroll
      for (int r = 0; r < 4; ++r) {
        int grow = row0 + wr * 64 + mi * 16 + quad * 4 + r;
        out1[(size_t)grow * F + gcol] = acc[mi][ni][r] + bias;
      }
    }
  }
}

// ---------------------------------------------------------------------------
// s[b,h,d,e] = sum_t q[t,d]*k[t,e] / 8, tril-masked. q,k bf16.
// ---------------------------------------------------------------------------
__global__ __launch_bounds__(256) void score_kernel(
    const unsigned short* __restrict__ qb, const unsigned short* __restrict__ kb,
    float* __restrict__ sb) {
  __shared__ float qs[64][65];
  __shared__ float ks[64][65];
  const int bh = blockIdx.x;
  const int tid = threadIdx.x;
  const size_t base = (size_t)bh * T * D;
  const int d0 = (tid >> 4) * 4, e0 = (tid & 15) * 4;
  float acc[4][4] = {};
  for (int ch = 0; ch < T / 64; ++ch) {
#pragma unroll
    for (int i = 0; i < 4; ++i) {
      int idx = (tid + i * 256) * 4;
      ushort4 qv = *(const ushort4*)&qb[base + (size_t)ch * 4096 + idx];
      ushort4 kv = *(const ushort4*)&kb[base + (size_t)ch * 4096 + idx];
      int r = idx >> 6, c = idx & 63;
      qs[r][c] = bf2f(qv.x); qs[r][c+1] = bf2f(qv.y);
      qs[r][c+2] = bf2f(qv.z); qs[r][c+3] = bf2f(qv.w);
      ks[r][c] = bf2f(kv.x); ks[r][c+1] = bf2f(kv.y);
      ks[r][c+2] = bf2f(kv.z); ks[r][c+3] = bf2f(kv.w);
    }
    __syncthreads();
#pragma unroll 8
    for (int tt = 0; tt < 64; ++tt) {
      float qa[4], kv[4];
#pragma unroll
      for (int i = 0; i < 4; ++i) qa[i] = qs[tt][d0 + i];
#pragma unroll
      for (int j = 0; j < 4; ++j) kv[j] = ks[tt][e0 + j];
#pragma unroll
      for (int i = 0; i < 4; ++i)
#pragma unroll
        for (int j = 0; j < 4; ++j) acc[i][j] += qa[i] * kv[j];
    }
    __syncthreads();
  }
#pragma unroll
  for (int i = 0; i < 4; ++i) {
#pragma unroll
    for (int j = 0; j < 4; ++j) {
      int dd = d0 + i, ee = e0 + j;
      float v = acc[i][j] * 0.125f;
      if (ee > dd) v = -10000.0f;
      sb[(size_t)bh * (D * D) + dd * D + ee] = v;
    }
  }
}

// ---------------------------------------------------------------------------
// exp_kernel: grid (tc, bh). thread = (lane=t within chunk, wave=dgroup).
// w[t,d] = (s[d,:].v[t,:])/4096 + mask[b,t];  e = exp(w) (no-max: |w|<~80 safe)
// writes e to wraw[bh][d][t] (transposed, coalesced) + per-(block,d) partial
// sums to sp[bh][tc][d]. v row held in VGPRs; s row is wave-uniform -> SGPRs.
// ---------------------------------------------------------------------------
__global__ __launch_bounds__(256) void exp_kernel(
    const float* __restrict__ vb, const float* __restrict__ sb,
    const float* __restrict__ mask, float* __restrict__ wraw,
    float* __restrict__ sp) {
  const int tc = blockIdx.x, bh = blockIdx.y;
  const int b = bh >> 4;
  const int tid = threadIdx.x;
  const int lane = tid & 63;
  const int dg = __builtin_amdgcn_readfirstlane(tid >> 6);
  const int tg = tc * 64 + lane;
  const float* vrow = vb + (size_t)bh * (T * D) + (size_t)tg * D;
  float4 vreg[16];
#pragma unroll
  for (int i = 0; i < 16; ++i) vreg[i] = *(const float4*)&vrow[i * 4];
  const float mval = mask[(size_t)b * T + tg];
  float ex[16];
#pragma unroll
  for (int dd = 0; dd < 16; ++dd) {
    const int d = dg * 16 + dd;
    const float* srow = sb + (size_t)bh * 4096 + (size_t)d * 64;
    float acc = 0.f;
#pragma unroll
    for (int e4 = 0; e4 < 16; ++e4) {
      float4 s4 = *(const float4*)&srow[e4 * 4];
      acc += s4.x * vreg[e4].x + s4.y * vreg[e4].y +
             s4.z * vreg[e4].z + s4.w * vreg[e4].w;
    }
    float w = acc * (1.0f / 4096.0f) + mval;
    ex[dd] = __expf(w);
    wraw[(size_t)bh * (T * D) + (size_t)d * T + tg] = ex[dd];
  }
  // per-wave (per-d) sum over the 64 t-lanes, deterministic butterfly
#pragma unroll
  for (int dd = 0; dd < 16; ++dd) {
    float v = ex[dd];
    v += __shfl_xor(v, 1, 64);
    v += __shfl_xor(v, 2, 64);
    v += __shfl_xor(v, 4, 64);
    v += __shfl_xor(v, 8, 64);
    v += __shfl_xor(v, 16, 64);
    v += __shfl_xor(v, 32, 64);
    if (lane == 0) sp[((size_t)bh * 16 + tc) * 64 + dg * 16 + dd] = v;
  }
}

// ---------------------------------------------------------------------------
// norm_kernel: grid (tc, bh). Reduce partials -> 1/S; stage wraw chunk via
// LDS (transpose back); write out2 = e/S and ab = bf16((e/S)*v), coalesced.
// ---------------------------------------------------------------------------
__global__ __launch_bounds__(256) void norm_kernel(
    const float* __restrict__ vb, const float* __restrict__ wraw,
    const float* __restrict__ sp, unsigned short* __restrict__ ab,
    float* __restrict__ out2) {
  __shared__ float wt[64][65];
  __shared__ float invS[64];
  const int tc = blockIdx.x, bh = blockIdx.y;
  const int b = bh >> 4, h = bh & 15;
  const int tid = threadIdx.x;
  if (tid < 64) {
    float S = 0.f;
#pragma unroll
    for (int j = 0; j < 16; ++j) S += sp[((size_t)bh * 16 + j) * 64 + tid];
    invS[tid] = 1.0f / S;
  }
#pragma unroll
  for (int i = 0; i < 16; ++i) {
    int idx = tid + i * 256;
    int dd = idx >> 6, tt = idx & 63;
    wt[dd][tt] = wraw[(size_t)bh * (T * D) + (size_t)dd * T + tc * 64 + tt];
  }
  __syncthreads();
  const int d = tid & 63, trow = tid >> 6;
#pragma unroll
  for (int j = 0; j < 16; ++j) {
    int tl = trow * 16 + j;
    int tg = tc * 64 + tl;
    float o = wt[d][tl] * invS[d];
    float vv = vb[(size_t)bh * (T * D) + (size_t)tg * D + d];
    size_t oidx = ((size_t)b * T + tg) * F + h * 64 + d;
    out2[oidx] = o;
    ab[oidx] = f2bf(o * vv);
  }
}

extern "C" void kernel_launch(void* const* d_in, const int* in_sizes, int n_in,
                              void* d_out, int out_size, void* d_ws,
                              size_t ws_size, hipStream_t stream) {
  const float* x = (const float*)d_in[0];
  const float* mask = (const float*)d_in[1];
  const float* Wa = (const float*)d_in[2];
  const float* ba = (const float*)d_in[3];
  const float* Wp = (const float*)d_in[4];
  const float* bp = (const float*)d_in[5];
  char* ws = (char*)d_ws;
  float* out = (float*)d_out;

  unsigned short* xhi = (unsigned short*)(ws + XHI_OFF);
  unsigned short* xlo = (unsigned short*)(ws + XLO_OFF);
  unsigned short* Wah = (unsigned short*)(ws + WAH_OFF);
  unsigned short* Wvl = (unsigned short*)(ws + WVL_OFF);
  unsigned short* qb  = (unsigned short*)(ws + QB_OFF);
  unsigned short* kb  = (unsigned short*)(ws + KB_OFF);
  float* sb   = (float*)(ws + SB_OFF);
  unsigned short* ab  = (unsigned short*)(ws + AB_OFF);
  unsigned short* Wpb = (unsigned short*)(ws + WPB_OFF);
  float* vb   = (float*)(ws + VB_OFF);     // overlays q,k (dead after score)
  float* wraw = (float*)(ws + WRAW_OFF);   // overlays x hi/lo (dead after v)
  float* sp   = (float*)(ws + SP_OFF);     // overlays Wv_lo (dead after v)

  cast_x<<<NT * F / 1024, 256, 0, stream>>>(x, xhi, xlo);
  tcast<<<dim3(QKV_COLS / 64, F / 64), 256, 0, stream>>>(Wa, Wah, Wvl,
                                                         QKV_COLS, 2048);
  tcast<<<dim3(F / 64, F / 64), 256, 0, stream>>>(Wp, Wpb, Wvl, F, 1 << 30);

  qk_mfma<<<dim3(2048 / 128, NT / 128), 256, 0, stream>>>(xhi, Wah, ba, qb, kb);

  score_kernel<<<dim3(B * H), 256, 0, stream>>>(qb, kb, sb);

  // q,k now dead -> vb overlays them
  v_mfma<<<dim3(F / 128, NT / 128), 256, 0, stream>>>(
      xhi, xlo, Wah + (size_t)2048 * 1024, Wvl, ba, vb);

  exp_kernel<<<dim3(T / 64, B * H), 256, 0, stream>>>(vb, sb, mask, wraw, sp);

  norm_kernel<<<dim3(T / 64, B * H), 256, 0, stream>>>(
      vb, wraw, sp, ab, out + (size_t)NT * F);

  proj_mfma<<<dim3(F / 128, NT / 128), 256, 0, stream>>>(ab, Wpb, bp, out);
}